// Round 8
// baseline (297.413 us; speedup 1.0000x reference)
//
#include <hip/hip_runtime.h>
#include <stdint.h>

typedef _Float16 f16x8 __attribute__((ext_vector_type(8)));
typedef float f32x4 __attribute__((ext_vector_type(4)));

__device__ __forceinline__ unsigned short f2h(float f) {
  _Float16 h = (_Float16)f;
  return __builtin_bit_cast(unsigned short, h);
}

#if __has_builtin(__builtin_amdgcn_global_load_lds)
#define HAVE_GLL 1
__device__ __forceinline__ void gload_lds16(const void* g, void* l) {
  auto gp = reinterpret_cast<const __attribute__((address_space(1))) void*>(
      reinterpret_cast<uintptr_t>(g));
  auto lp = reinterpret_cast<__attribute__((address_space(3))) void*>(
      reinterpret_cast<uintptr_t>(l));
  __builtin_amdgcn_global_load_lds(gp, lp, 16, 0, 0);
}
#else
#define HAVE_GLL 0
#endif

// ---------------- fused setup ----------------
__device__ __forceinline__ void transpose_core(const float* in, unsigned short* out,
                                               int R, int C, int c0, int r0) {
  __shared__ float t[32][33];
  int tx = threadIdx.x & 31, ty = threadIdx.x >> 5;  // 32 x 8
#pragma unroll
  for (int i = 0; i < 32; i += 8)
    t[ty + i][tx] = in[(long)(r0 + ty + i) * C + (c0 + tx)];
  __syncthreads();
#pragma unroll
  for (int i = 0; i < 32; i += 8)
    out[(long)(c0 + ty + i) * R + (r0 + tx)] = f2h(t[tx][ty + i]);
}

// grid (128,16,5): z=0 Wq^T, z=1 Wk^T (both [512,4096]->[4096,512]);
// z=2 Wu [4096,512]->[512,4096]; z=3 convert x (fp32->fp16); z=4 convert Wv.
__global__ __launch_bounds__(256) void k_setup(
    const float* __restrict__ x, const float* __restrict__ Wq, const float* __restrict__ Wk,
    const float* __restrict__ Wv, const float* __restrict__ Wu,
    unsigned short* __restrict__ Xh, unsigned short* __restrict__ Wqt,
    unsigned short* __restrict__ Wkt, unsigned short* __restrict__ Wvh,
    unsigned short* __restrict__ Wut) {
  int z = blockIdx.z;
  if (z == 0) {
    transpose_core(Wq, Wqt, 512, 4096, blockIdx.x * 32, blockIdx.y * 32);
  } else if (z == 1) {
    transpose_core(Wk, Wkt, 512, 4096, blockIdx.x * 32, blockIdx.y * 32);
  } else if (z == 2) {
    transpose_core(Wu, Wut, 4096, 512, blockIdx.y * 32, blockIdx.x * 32);
  } else {
    const float* in = (z == 3) ? x : Wv;
    unsigned short* out = (z == 3) ? Xh : Wvh;
    int i = (blockIdx.y * 128 + blockIdx.x) * 256 + threadIdx.x;
    float4 v = reinterpret_cast<const float4*>(in)[i];
    ushort4 o;
    o.x = f2h(v.x); o.y = f2h(v.y); o.z = f2h(v.z); o.w = f2h(v.w);
    reinterpret_cast<ushort4*>(out)[i] = o;
  }
}

// ---------------- GEMM core: C[M,N] = A[M,K] * B[N,K]^T ----------------
// 128x128 tile, BK=64, 256 threads (4 waves, 2x2 of 64x64), mfma 16x16x32 f16.
// LDS XOR-swizzled at 16B granularity; staging via global_load_lds(16B).
// OUT: 0 fp32 store, 1 fp16 store, 2 fp32 atomicAdd, 3 fp16 VU-scatter
// (row=(h,e): h=row>>9,e=row&511; col=(b,j): b=col>>10,j=col&1023 ->
//  addr = b*4194304 + e*8192 + h*1024 + j, i.e. VU[b][e][h*1024+j]).
template <int OUT>
__device__ __forceinline__ void gemm_core(const unsigned short* __restrict__ A,
                                          const unsigned short* __restrict__ B,
                                          void* __restrict__ Cv, int K, int lda, int ldb,
                                          int ldc, long coff, int m0, int n0) {
  __shared__ unsigned short As[128 * 64];
  __shared__ unsigned short Bs[128 * 64];

  int tid = threadIdx.x;
  int wid = tid >> 6, lane = tid & 63;
  int wm = (wid >> 1) * 64, wn = (wid & 1) * 64;
  int rq = lane >> 4, rl = lane & 15;

  f32x4 acc[4][4];
#pragma unroll
  for (int i = 0; i < 4; ++i)
#pragma unroll
    for (int j = 0; j < 4; ++j) acc[i][j] = (f32x4){0.f, 0.f, 0.f, 0.f};

#if HAVE_GLL
  int cg = (lane & 7) ^ ((lane >> 3) & 7);  // permuted global chunk -> swizzled LDS
  int rl8 = lane >> 3;                      // row within 8-row group
#endif

  for (int k0 = 0; k0 < K; k0 += 64) {
    __syncthreads();
#if HAVE_GLL
#pragma unroll
    for (int t = 0; t < 4; ++t) {
      int r = wid * 32 + t * 8;  // uniform slab base row
      gload_lds16(&A[(long)(m0 + r + rl8) * lda + k0 + cg * 8], &As[r * 64]);
      gload_lds16(&B[(long)(n0 + r + rl8) * ldb + k0 + cg * 8], &Bs[r * 64]);
    }
#else
#pragma unroll
    for (int it = 0; it < 4; ++it) {
      int idx = tid + it * 256;
      int r = idx >> 3, c = idx & 7;
      int cs = c ^ (r & 7);
      *reinterpret_cast<uint4*>(&As[r * 64 + cs * 8]) =
          *reinterpret_cast<const uint4*>(&A[(long)(m0 + r) * lda + k0 + c * 8]);
      *reinterpret_cast<uint4*>(&Bs[r * 64 + cs * 8]) =
          *reinterpret_cast<const uint4*>(&B[(long)(n0 + r) * ldb + k0 + c * 8]);
    }
#endif
    __syncthreads();
#pragma unroll
    for (int ks = 0; ks < 2; ++ks) {
      f16x8 af[4], bfr[4];
      int kc = ks * 4 + rq;
#pragma unroll
      for (int i = 0; i < 4; ++i) {
        int ra = wm + i * 16 + rl;
        af[i] = *reinterpret_cast<const f16x8*>(&As[ra * 64 + ((kc ^ (ra & 7)) << 3)]);
        int rb = wn + i * 16 + rl;
        bfr[i] = *reinterpret_cast<const f16x8*>(&Bs[rb * 64 + ((kc ^ (rb & 7)) << 3)]);
      }
#pragma unroll
      for (int i = 0; i < 4; ++i)
#pragma unroll
        for (int j = 0; j < 4; ++j)
          acc[i][j] = __builtin_amdgcn_mfma_f32_16x16x32_f16(af[i], bfr[j], acc[i][j], 0, 0, 0);
    }
  }

#pragma unroll
  for (int i = 0; i < 4; ++i)
#pragma unroll
    for (int j = 0; j < 4; ++j)
#pragma unroll
      for (int r = 0; r < 4; ++r) {
        int row = m0 + wm + i * 16 + rq * 4 + r;
        int col = n0 + wn + j * 16 + rl;
        float v = acc[i][j][r];
        if (OUT == 1)
          reinterpret_cast<unsigned short*>(Cv)[coff + (long)row * ldc + col] = f2h(v);
        else if (OUT == 0)
          reinterpret_cast<float*>(Cv)[coff + (long)row * ldc + col] = v;
        else if (OUT == 2)
          atomicAdd(&reinterpret_cast<float*>(Cv)[coff + (long)row * ldc + col], v);
        else {
          long addr = (long)(col >> 10) * 4194304 + (long)(row & 511) * 8192 +
                      ((row >> 9) << 10) + (col & 1023);
          reinterpret_cast<unsigned short*>(Cv)[addr] = f2h(v);
        }
      }
}

// XCD-swizzled batched A*B^T. grid (8, W): linear id = c + 8*w -> XCD c; all
// blocks of z land on XCD z%8, consecutive in that XCD's dispatch order.
// z = c + 8*(w >> (sx+sy)); y = (w >> sx) & (2^sy-1); x = w & (2^sx-1).
template <int OUT>
__global__ __launch_bounds__(256, 2) void k_gemm_btx(
    const unsigned short* __restrict__ A, const unsigned short* __restrict__ B,
    void* __restrict__ Cv, int K, int lda, int ldb, int ldc,
    long oAo, long oAi, long oBo, long oBi, long oCo, long oCi, int zdiv,
    int sx, int sy) {
  int c = blockIdx.x, w = blockIdx.y;
  int z = c + 8 * (w >> (sx + sy));
  int y = (w >> sx) & ((1 << sy) - 1);
  int x = w & ((1 << sx) - 1);
  A += (long)(z / zdiv) * oAo + (long)(z % zdiv) * oAi;
  B += (long)(z / zdiv) * oBo + (long)(z % zdiv) * oBi;
  long coff = (long)(z / zdiv) * oCo + (long)(z % zdiv) * oCi;
  gemm_core<OUT>(A, B, Cv, K, lda, ldb, ldc, coff, y * 128, x * 128);
}

// fused Q/K/VU projection: grid (8, 384). z = w/128 in {0:Q, 1:K, 2:VU}.
// z<2 : C[bt][hd] = X . W^T, col-tile x head-aligned to XCD.
// z==2: VU^T[he][bj] = Wvut . X^T -> scattered to VU[b][e][h*1024+j] (OUT=3).
__global__ __launch_bounds__(256, 2) void k_gemm_qkv(
    const unsigned short* __restrict__ X, const unsigned short* __restrict__ Wqt,
    const unsigned short* __restrict__ Wkt, const unsigned short* __restrict__ Wvut,
    unsigned short* __restrict__ Qb, unsigned short* __restrict__ Kb,
    unsigned short* __restrict__ VUb) {
  int c = blockIdx.x, w = blockIdx.y;
  int z = w >> 7;
  int r = w & 127;
  if (z < 2) {
    int x = 4 * c + (r & 3), y = r >> 2;
    gemm_core<1>(X, (z == 0) ? Wqt : Wkt, (z == 0) ? Qb : Kb, 512, 512, 512, 4096, 0,
                 y * 128, x * 128);
  } else {
    int y = 4 * c + (r & 3), x = r >> 2;
    gemm_core<3>(Wvut, X, VUb, 512, 512, 512, 0, 0, y * 128, x * 128);
  }
}

// ---------------- softmax: one wave per 1024-chunk, P[b][i][h*1024+j] ----------------
// grid (8,1024): h = blockIdx.x (XCD-aligned with the S-gemm writer), 4 waves/block
// over g = (b,i).
__global__ __launch_bounds__(256) void k_softmax_x(unsigned short* __restrict__ S) {
  int g = blockIdx.y * 4 + (threadIdx.x >> 6);
  int b = g >> 10, i = g & 1023;
  long base = (long)b * 8388608 + (long)i * 8192 + (long)blockIdx.x * 1024;
  int lane = threadIdx.x & 63;
  f16x8* p = reinterpret_cast<f16x8*>(S + base);
  f16x8 a = p[lane * 2], bb = p[lane * 2 + 1];
  float v[16];
#pragma unroll
  for (int q = 0; q < 8; ++q) { v[q] = (float)a[q]; v[8 + q] = (float)bb[q]; }
  float m = v[0];
#pragma unroll
  for (int q = 1; q < 16; ++q) m = fmaxf(m, v[q]);
#pragma unroll
  for (int o = 32; o; o >>= 1) m = fmaxf(m, __shfl_xor(m, o));
  float s = 0.f;
#pragma unroll
  for (int q = 0; q < 16; ++q) { v[q] = __expf(v[q] - m); s += v[q]; }
#pragma unroll
  for (int o = 32; o; o >>= 1) s += __shfl_xor(s, o);
  float inv = 1.0f / s;
  f16x8 oa, ob;
#pragma unroll
  for (int q = 0; q < 8; ++q) {
    oa[q] = (_Float16)(v[q] * inv);
    ob[q] = (_Float16)(v[8 + q] * inv);
  }
  p[lane * 2] = oa;
  p[lane * 2 + 1] = ob;
}

__global__ void k_sentinel(float* out, float v) { out[0] = v; }

extern "C" void kernel_launch(void* const* d_in, const int* in_sizes, int n_in,
                              void* d_out, int out_size, void* d_ws, size_t ws_size,
                              hipStream_t stream) {
  // setup_inputs dict order: x, Wk, Wq, Wv, Wu
  const float* x  = (const float*)d_in[0];
  const float* Wk = (const float*)d_in[1];
  const float* Wq = (const float*)d_in[2];
  const float* Wv = (const float*)d_in[3];
  const float* Wu = (const float*)d_in[4];
  float* out = (float*)d_out;

  const long SZ_X = 4096L * 512;
  const long SZ_W = 512L * 4096;
  const size_t NEED = 188743680;  // 180 MiB exactly (verified fits)

  if (ws_size < NEED) {
    hipMemsetAsync(d_out, 0, (size_t)out_size * 4, stream);
    k_sentinel<<<1, 1, 0, stream>>>(out, (float)ws_size);
    return;
  }

  char* p = (char*)d_ws;
  unsigned short* Xbf  = (unsigned short*)p; p += SZ_X * 2;          //  4 MiB
  unsigned short* Wqt  = (unsigned short*)p; p += SZ_W * 2;          //  4 MiB
  unsigned short* Wkt  = (unsigned short*)p; p += SZ_W * 2;          //  4 MiB
  unsigned short* Wut  = (unsigned short*)p; p += SZ_W * 2;          //  4 MiB
  unsigned short* Wvut = (unsigned short*)p; p += SZ_W * 2;          //  4 MiB [h][e][k]
  unsigned short* Qb   = (unsigned short*)p; p += 4096L * 4096 * 2;  // 32 MiB
  unsigned short* Kb   = (unsigned short*)p; p += 4096L * 4096 * 2;  // 32 MiB
  unsigned short* Pb   = (unsigned short*)p; p += 4096L * 8192 * 2;  // 64 MiB [b][i][h*1024+j]
  unsigned short* VUb  = (unsigned short*)p;                         // 32 MiB [b][e][h*1024+j]
  unsigned short* Wvh  = VUb;  // 4 MiB alias: dead before VUb is written

  // zero d_out early (final gemm atomicAdds into it)
  hipMemsetAsync(d_out, 0, (size_t)out_size * 4, stream);

  // ---- setup: Wq^T, Wk^T, Wu^T, convert x, convert Wv ----
  k_setup<<<dim3(128, 16, 5), 256, 0, stream>>>(x, Wq, Wk, Wv, Wu, Xbf, Wqt, Wkt, Wvh, Wut);

  // ---- Wvut[h][e][k] = sum_d Wut[e, h*512+d] * Wvh[k, h*512+d]  (2.1 GF) ----
  k_gemm_btx<1><<<dim3(8, 16), 256, 0, stream>>>(
      Wut, Wvh, Wvut, 512, 4096, 4096, 512,
      512, 0, 512, 0, 262144, 0, 1, 2, 2);

  // ---- Q/K projections + VU = X . Wvu (scattered to VU[b][e][h*1024+j]) ----
  k_gemm_qkv<<<dim3(8, 384), 256, 0, stream>>>(Xbf, Wqt, Wkt, Wvut, Qb, Kb, VUb);

  // ---- S: P[b][i][h*1024+j] = K[b,i,h,:] . Q[b,j,h,:]  (fp16, ldc=8192) ----
  k_gemm_btx<1><<<dim3(8, 256), 256, 0, stream>>>(
      Kb, Qb, Pb, 512, 4096, 4096, 8192,
      4194304, 512, 4194304, 512, 8388608, 1024, 8, 3, 3);

  // ---- softmax over each 1024-chunk of P, in place ----
  k_softmax_x<<<dim3(8, 1024), 256, 0, stream>>>(Pb);

  // ---- out[b,i,e] += sum_{kk} Pb[b][i][kk] * VUb[b][e][kk], split-K x4 (h-pairs) ----
  k_gemm_btx<2><<<dim3(8, 64), 256, 0, stream>>>(
      Pb, VUb, out, 2048, 8192, 8192, 512,
      8388608, 2048, 4194304, 2048, 524288, 0, 4, 2, 3);
}

// Round 9
// 283.381 us; speedup vs baseline: 1.0495x; 1.0495x over previous
//
#include <hip/hip_runtime.h>
#include <stdint.h>

typedef _Float16 f16x8 __attribute__((ext_vector_type(8)));
typedef float f32x4 __attribute__((ext_vector_type(4)));

__device__ __forceinline__ unsigned short f2h(float f) {
  _Float16 h = (_Float16)f;
  return __builtin_bit_cast(unsigned short, h);
}

#if __has_builtin(__builtin_amdgcn_global_load_lds)
#define HAVE_GLL 1
__device__ __forceinline__ void gload_lds16(const void* g, void* l) {
  auto gp = reinterpret_cast<const __attribute__((address_space(1))) void*>(
      reinterpret_cast<uintptr_t>(g));
  auto lp = reinterpret_cast<__attribute__((address_space(3))) void*>(
      reinterpret_cast<uintptr_t>(l));
  __builtin_amdgcn_global_load_lds(gp, lp, 16, 0, 0);
}
#else
#define HAVE_GLL 0
#endif

// ---------------- fused setup ----------------
__device__ __forceinline__ void transpose_core(const float* in, unsigned short* out,
                                               int R, int C, int c0, int r0) {
  __shared__ float t[32][33];
  int tx = threadIdx.x & 31, ty = threadIdx.x >> 5;  // 32 x 8
#pragma unroll
  for (int i = 0; i < 32; i += 8)
    t[ty + i][tx] = in[(long)(r0 + ty + i) * C + (c0 + tx)];
  __syncthreads();
#pragma unroll
  for (int i = 0; i < 32; i += 8)
    out[(long)(c0 + ty + i) * R + (r0 + tx)] = f2h(t[tx][ty + i]);
}

// grid (128,16,5): z=0 Wq^T, z=1 Wk^T ([512,4096]->[4096,512]);
// z=2 Wu [4096,512]->[512,4096]; z=3 convert x; z=4 convert Wv.
__global__ __launch_bounds__(256) void k_setup(
    const float* __restrict__ x, const float* __restrict__ Wq, const float* __restrict__ Wk,
    const float* __restrict__ Wv, const float* __restrict__ Wu,
    unsigned short* __restrict__ Xh, unsigned short* __restrict__ Wqt,
    unsigned short* __restrict__ Wkt, unsigned short* __restrict__ Wvh,
    unsigned short* __restrict__ Wut) {
  int z = blockIdx.z;
  if (z == 0) {
    transpose_core(Wq, Wqt, 512, 4096, blockIdx.x * 32, blockIdx.y * 32);
  } else if (z == 1) {
    transpose_core(Wk, Wkt, 512, 4096, blockIdx.x * 32, blockIdx.y * 32);
  } else if (z == 2) {
    transpose_core(Wu, Wut, 4096, 512, blockIdx.y * 32, blockIdx.x * 32);
  } else {
    const float* in = (z == 3) ? x : Wv;
    unsigned short* out = (z == 3) ? Xh : Wvh;
    int i = (blockIdx.y * 128 + blockIdx.x) * 256 + threadIdx.x;
    float4 v = reinterpret_cast<const float4*>(in)[i];
    ushort4 o;
    o.x = f2h(v.x); o.y = f2h(v.y); o.z = f2h(v.z); o.w = f2h(v.w);
    reinterpret_cast<ushort4*>(out)[i] = o;
  }
}

// ---------------- GEMM core: C[M,N] = A[M,K] * B[N,K]^T ----------------
// 128x128 tile, BK=64, 256 threads (4 waves, 2x2 of 64x64), mfma 16x16x32 f16.
// LDS XOR-swizzled at 16B granularity; staging via global_load_lds(16B).
// LDS buffers are passed IN from the kernel so multiple template instantiations
// inside one kernel share a single 32 KiB allocation (declaring them here would
// duplicate LDS per inlined instance -> 64 KiB -> halved occupancy; seen R8).
// OUT: 0 fp32 store, 1 fp16 store, 2 fp32 atomicAdd, 3 fp16 VU-scatter
// (row=(h,e): addr = b*4194304 + e*8192 + h*1024 + j, i.e. VU[b][e][h*1024+j]).
template <int OUT>
__device__ __forceinline__ void gemm_core(unsigned short* __restrict__ As,
                                          unsigned short* __restrict__ Bs,
                                          const unsigned short* __restrict__ A,
                                          const unsigned short* __restrict__ B,
                                          void* __restrict__ Cv, int K, int lda, int ldb,
                                          int ldc, long coff, int m0, int n0) {
  int tid = threadIdx.x;
  int wid = tid >> 6, lane = tid & 63;
  int wm = (wid >> 1) * 64, wn = (wid & 1) * 64;
  int rq = lane >> 4, rl = lane & 15;

  f32x4 acc[4][4];
#pragma unroll
  for (int i = 0; i < 4; ++i)
#pragma unroll
    for (int j = 0; j < 4; ++j) acc[i][j] = (f32x4){0.f, 0.f, 0.f, 0.f};

#if HAVE_GLL
  int cg = (lane & 7) ^ ((lane >> 3) & 7);  // permuted global chunk -> swizzled LDS
  int rl8 = lane >> 3;                      // row within 8-row group
#endif

  for (int k0 = 0; k0 < K; k0 += 64) {
    __syncthreads();
#if HAVE_GLL
#pragma unroll
    for (int t = 0; t < 4; ++t) {
      int r = wid * 32 + t * 8;  // uniform slab base row
      gload_lds16(&A[(long)(m0 + r + rl8) * lda + k0 + cg * 8], &As[r * 64]);
      gload_lds16(&B[(long)(n0 + r + rl8) * ldb + k0 + cg * 8], &Bs[r * 64]);
    }
#else
#pragma unroll
    for (int it = 0; it < 4; ++it) {
      int idx = tid + it * 256;
      int r = idx >> 3, c = idx & 7;
      int cs = c ^ (r & 7);
      *reinterpret_cast<uint4*>(&As[r * 64 + cs * 8]) =
          *reinterpret_cast<const uint4*>(&A[(long)(m0 + r) * lda + k0 + c * 8]);
      *reinterpret_cast<uint4*>(&Bs[r * 64 + cs * 8]) =
          *reinterpret_cast<const uint4*>(&B[(long)(n0 + r) * ldb + k0 + c * 8]);
    }
#endif
    __syncthreads();
#pragma unroll
    for (int ks = 0; ks < 2; ++ks) {
      f16x8 af[4], bfr[4];
      int kc = ks * 4 + rq;
#pragma unroll
      for (int i = 0; i < 4; ++i) {
        int ra = wm + i * 16 + rl;
        af[i] = *reinterpret_cast<const f16x8*>(&As[ra * 64 + ((kc ^ (ra & 7)) << 3)]);
        int rb = wn + i * 16 + rl;
        bfr[i] = *reinterpret_cast<const f16x8*>(&Bs[rb * 64 + ((kc ^ (rb & 7)) << 3)]);
      }
#pragma unroll
      for (int i = 0; i < 4; ++i)
#pragma unroll
        for (int j = 0; j < 4; ++j)
          acc[i][j] = __builtin_amdgcn_mfma_f32_16x16x32_f16(af[i], bfr[j], acc[i][j], 0, 0, 0);
    }
  }

#pragma unroll
  for (int i = 0; i < 4; ++i)
#pragma unroll
    for (int j = 0; j < 4; ++j)
#pragma unroll
      for (int r = 0; r < 4; ++r) {
        int row = m0 + wm + i * 16 + rq * 4 + r;
        int col = n0 + wn + j * 16 + rl;
        float v = acc[i][j][r];
        if (OUT == 1)
          reinterpret_cast<unsigned short*>(Cv)[coff + (long)row * ldc + col] = f2h(v);
        else if (OUT == 0)
          reinterpret_cast<float*>(Cv)[coff + (long)row * ldc + col] = v;
        else if (OUT == 2)
          atomicAdd(&reinterpret_cast<float*>(Cv)[coff + (long)row * ldc + col], v);
        else {
          long addr = (long)(col >> 10) * 4194304 + (long)(row & 511) * 8192 +
                      ((row >> 9) << 10) + (col & 1023);
          reinterpret_cast<unsigned short*>(Cv)[addr] = f2h(v);
        }
      }
}

#define DECL_LDS \
  __shared__ unsigned short As[128 * 64]; \
  __shared__ unsigned short Bs[128 * 64];

// XCD-swizzled batched A*B^T. grid (8, W): linear id = c + 8*w -> XCD c; all
// blocks of z land on XCD z%8, consecutive in that XCD's dispatch order.
template <int OUT>
__global__ __launch_bounds__(256, 2) void k_gemm_btx(
    const unsigned short* __restrict__ A, const unsigned short* __restrict__ B,
    void* __restrict__ Cv, int K, int lda, int ldb, int ldc,
    long oAo, long oAi, long oBo, long oBi, long oCo, long oCi, int zdiv,
    int sx, int sy) {
  DECL_LDS
  int c = blockIdx.x, w = blockIdx.y;
  int z = c + 8 * (w >> (sx + sy));
  int y = (w >> sx) & ((1 << sy) - 1);
  int x = w & ((1 << sx) - 1);
  A += (long)(z / zdiv) * oAo + (long)(z % zdiv) * oAi;
  B += (long)(z / zdiv) * oBo + (long)(z % zdiv) * oBi;
  long coff = (long)(z / zdiv) * oCo + (long)(z % zdiv) * oCi;
  gemm_core<OUT>(As, Bs, A, B, Cv, K, lda, ldb, ldc, coff, y * 128, x * 128);
}

// fused Q/K/VU projection: grid (8, 384). z = w/128 in {0:Q, 1:K, 2:VU}.
// z<2 : C[bt][hd] = X . W^T, col-tile x head-aligned to XCD.
// z==2: VU^T[he][bj] = Wvut . X^T -> scattered to VU[b][e][h*1024+j] (OUT=3).
// Both instantiations share one LDS allocation (As/Bs passed in).
__global__ __launch_bounds__(256, 2) void k_gemm_qkv(
    const unsigned short* __restrict__ X, const unsigned short* __restrict__ Wqt,
    const unsigned short* __restrict__ Wkt, const unsigned short* __restrict__ Wvut,
    unsigned short* __restrict__ Qb, unsigned short* __restrict__ Kb,
    unsigned short* __restrict__ VUb) {
  DECL_LDS
  int c = blockIdx.x, w = blockIdx.y;
  int z = w >> 7;
  int r = w & 127;
  if (z < 2) {
    int x = 4 * c + (r & 3), y = r >> 2;
    gemm_core<1>(As, Bs, X, (z == 0) ? Wqt : Wkt, (z == 0) ? Qb : Kb, 512, 512, 512,
                 4096, 0, y * 128, x * 128);
  } else {
    int y = 4 * c + (r & 3), x = r >> 2;
    gemm_core<3>(As, Bs, Wvut, X, VUb, 512, 512, 512, 0, 0, y * 128, x * 128);
  }
}

// O-final: out[b,i,e] += sum_kk Pb[b][i][kk] * VUb[b][e][kk]. grid (8,64).
// Group g = (b, kchunk, ihalf): per-group working set = P slab 512x2048x2 (2 MiB)
// + VU slab 512x2048x2 (2 MiB) = 4 MiB = one XCD L2. XCD = g%8 = (kchunk*2+ihalf)
// which matches where the S-gemm / VU writers put those k-chunks (heads 2kc,2kc+1
// live on XCDs 2kc,2kc+1). atomicAdd into pre-zeroed fp32 out (4 adds/elem).
__global__ __launch_bounds__(256, 2) void k_gemm_out(
    const unsigned short* __restrict__ Pb, const unsigned short* __restrict__ VUb,
    float* __restrict__ out) {
  DECL_LDS
  int c = blockIdx.x, w = blockIdx.y;
  int g = c + 8 * (w >> 4);  // 0..31
  int r = w & 15;
  int b = g >> 3, kc = (g >> 1) & 3, ih = g & 1;
  int y = ih * 4 + (r >> 2);  // 0..7
  int x = r & 3;              // 0..3
  gemm_core<2>(As, Bs, Pb + (long)b * 8388608 + kc * 2048,
               VUb + (long)b * 4194304 + kc * 2048, out, 2048, 8192, 8192, 512,
               (long)b * 524288, y * 128, x * 128);
}

// ---------------- softmax: one wave per 1024-chunk, P[b][i][h*1024+j] ----------------
// grid (8,1024): h = blockIdx.x (XCD-aligned with the S-gemm writer).
__global__ __launch_bounds__(256) void k_softmax_x(unsigned short* __restrict__ S) {
  int g = blockIdx.y * 4 + (threadIdx.x >> 6);
  int b = g >> 10, i = g & 1023;
  long base = (long)b * 8388608 + (long)i * 8192 + (long)blockIdx.x * 1024;
  int lane = threadIdx.x & 63;
  f16x8* p = reinterpret_cast<f16x8*>(S + base);
  f16x8 a = p[lane * 2], bb = p[lane * 2 + 1];
  float v[16];
#pragma unroll
  for (int q = 0; q < 8; ++q) { v[q] = (float)a[q]; v[8 + q] = (float)bb[q]; }
  float m = v[0];
#pragma unroll
  for (int q = 1; q < 16; ++q) m = fmaxf(m, v[q]);
#pragma unroll
  for (int o = 32; o; o >>= 1) m = fmaxf(m, __shfl_xor(m, o));
  float s = 0.f;
#pragma unroll
  for (int q = 0; q < 16; ++q) { v[q] = __expf(v[q] - m); s += v[q]; }
#pragma unroll
  for (int o = 32; o; o >>= 1) s += __shfl_xor(s, o);
  float inv = 1.0f / s;
  f16x8 oa, ob;
#pragma unroll
  for (int q = 0; q < 8; ++q) {
    oa[q] = (_Float16)(v[q] * inv);
    ob[q] = (_Float16)(v[8 + q] * inv);
  }
  p[lane * 2] = oa;
  p[lane * 2 + 1] = ob;
}

__global__ void k_sentinel(float* out, float v) { out[0] = v; }

extern "C" void kernel_launch(void* const* d_in, const int* in_sizes, int n_in,
                              void* d_out, int out_size, void* d_ws, size_t ws_size,
                              hipStream_t stream) {
  // setup_inputs dict order: x, Wk, Wq, Wv, Wu
  const float* x  = (const float*)d_in[0];
  const float* Wk = (const float*)d_in[1];
  const float* Wq = (const float*)d_in[2];
  const float* Wv = (const float*)d_in[3];
  const float* Wu = (const float*)d_in[4];
  float* out = (float*)d_out;

  const long SZ_X = 4096L * 512;
  const long SZ_W = 512L * 4096;
  const size_t NEED = 188743680;  // 180 MiB exactly (verified fits)

  if (ws_size < NEED) {
    hipMemsetAsync(d_out, 0, (size_t)out_size * 4, stream);
    k_sentinel<<<1, 1, 0, stream>>>(out, (float)ws_size);
    return;
  }

  char* p = (char*)d_ws;
  unsigned short* Xbf  = (unsigned short*)p; p += SZ_X * 2;          //  4 MiB
  unsigned short* Wqt  = (unsigned short*)p; p += SZ_W * 2;          //  4 MiB
  unsigned short* Wkt  = (unsigned short*)p; p += SZ_W * 2;          //  4 MiB
  unsigned short* Wut  = (unsigned short*)p; p += SZ_W * 2;          //  4 MiB
  unsigned short* Wvut = (unsigned short*)p; p += SZ_W * 2;          //  4 MiB [h][e][k]
  unsigned short* Qb   = (unsigned short*)p; p += 4096L * 4096 * 2;  // 32 MiB
  unsigned short* Kb   = (unsigned short*)p; p += 4096L * 4096 * 2;  // 32 MiB
  unsigned short* Pb   = (unsigned short*)p; p += 4096L * 8192 * 2;  // 64 MiB [b][i][h*1024+j]
  unsigned short* VUb  = (unsigned short*)p;                         // 32 MiB [b][e][h*1024+j]
  unsigned short* Wvh  = VUb;  // 4 MiB alias: dead before VUb is written

  // zero d_out early (final gemm atomicAdds into it)
  hipMemsetAsync(d_out, 0, (size_t)out_size * 4, stream);

  // ---- setup: Wq^T, Wk^T, Wu^T, convert x, convert Wv ----
  k_setup<<<dim3(128, 16, 5), 256, 0, stream>>>(x, Wq, Wk, Wv, Wu, Xbf, Wqt, Wkt, Wvh, Wut);

  // ---- Wvut[h][e][k] = sum_d Wut[e, h*512+d] * Wvh[k, h*512+d]  (2.1 GF) ----
  k_gemm_btx<1><<<dim3(8, 16), 256, 0, stream>>>(
      Wut, Wvh, Wvut, 512, 4096, 4096, 512,
      512, 0, 512, 0, 262144, 0, 1, 2, 2);

  // ---- Q/K projections + VU = X . Wvu (scattered to VU[b][e][h*1024+j]) ----
  k_gemm_qkv<<<dim3(8, 384), 256, 0, stream>>>(Xbf, Wqt, Wkt, Wvut, Qb, Kb, VUb);

  // ---- S: P[b][i][h*1024+j] = K[b,i,h,:] . Q[b,j,h,:]  (fp16, ldc=8192) ----
  k_gemm_btx<1><<<dim3(8, 256), 256, 0, stream>>>(
      Kb, Qb, Pb, 512, 4096, 4096, 8192,
      4194304, 512, 4194304, 512, 8388608, 1024, 8, 3, 3);

  // ---- softmax over each 1024-chunk of P, in place ----
  k_softmax_x<<<dim3(8, 1024), 256, 0, stream>>>(Pb);

  // ---- out = P . VU^T with L2-sized (b,kchunk,ihalf) groups, atomicAdd ----
  k_gemm_out<<<dim3(8, 64), 256, 0, stream>>>(Pb, VUb, out);
}